// Round 20
// baseline (611.853 us; speedup 1.0000x reference)
//
#include <hip/hip_runtime.h>
#include <hip/hip_fp16.h>
#include <math.h>

#define N_NODES 16384
#define N_EDGES 524288
#define N_GRAPHS 64
#define HID 128
#define FILT 128
#define NG 51
#define NL 6
#define TROWS 2048   // filter-table resolution
#define DMAX 8.66025404f          // 5*sqrt(3), max possible distance
#define DSTEP (DMAX / (TROWS - 1))
#define INV_DSTEP ((TROWS - 1) / DMAX)
#define EU 3         // edge-pair unroll (6 edges in flight)
#define TSTRIDE 132  // LDS row stride (pad; keeps float2 8B-aligned)

__device__ __forceinline__ float ssp(float x) {
    float sp = (x > 20.0f) ? x : log1pf(__expf(x));
    return sp - 0.6931471805599453f;
}

__global__ void k_embed(const int* __restrict__ z, const float* __restrict__ emb,
                        float* __restrict__ h) {
    int i = blockIdx.x * blockDim.x + threadIdx.x;
    int n = i >> 7, c = i & 127;
    h[i] = emb[z[n] * HID + c];
}

__global__ void k_hist(const int* __restrict__ ei, int* __restrict__ cnt) {
    int e = blockIdx.x * blockDim.x + threadIdx.x;
    if (e < N_EDGES) atomicAdd(&cnt[ei[e]], 1);
}

__global__ __launch_bounds__(1024) void k_scan(const int* __restrict__ cnt,
                                               int* __restrict__ rowptr,
                                               int* __restrict__ wo) {
    __shared__ int sums[1024];
    int t = threadIdx.x;
    int loc[16];
    int s = 0;
    #pragma unroll
    for (int i = 0; i < 16; ++i) { loc[i] = cnt[t * 16 + i]; s += loc[i]; }
    sums[t] = s;
    __syncthreads();
    for (int off = 1; off < 1024; off <<= 1) {
        int v = sums[t];
        int u = (t >= off) ? sums[t - off] : 0;
        __syncthreads();
        sums[t] = v + u;
        __syncthreads();
    }
    int ex = sums[t] - s;
    #pragma unroll
    for (int i = 0; i < 16; ++i) {
        rowptr[t * 16 + i] = ex;
        wo[t * 16 + i] = ex;
        ex += loc[i];
    }
    if (t == 1023) rowptr[16384] = ex;
}

// scatter into CSR order: meta.x = col, meta.y = ew bits
__global__ void k_scatter(const int* __restrict__ ei, const float* __restrict__ pos,
                          int* __restrict__ wo, int2* __restrict__ meta) {
    int e = blockIdx.x * blockDim.x + threadIdx.x;
    if (e >= N_EDGES) return;
    int r = ei[e], c = ei[N_EDGES + e];
    int p = atomicAdd(&wo[r], 1);
    float dx = pos[r * 3 + 0] - pos[c * 3 + 0];
    float dy = pos[r * 3 + 1] - pos[c * 3 + 1];
    float dz = pos[r * 3 + 2] - pos[c * 3 + 2];
    float ew = sqrtf(dx * dx + dy * dy + dz * dz);
    meta[p] = make_int2(c, __float_as_int(ew));
}

// Pack fp32 [nmat][128][128] weights into fp16 k-pair layout:
// dst[mat*8192 + k2*128 + c] = half2(W[2k2][c], W[2k2+1][c])
__global__ void k_wcvt(const float* __restrict__ src, __half2* __restrict__ dst,
                       int n) {
    int i = blockIdx.x * 256 + threadIdx.x;
    if (i >= n) return;
    int mat = i >> 13;
    int r = i & 8191;
    int k2 = r >> 7;
    int c = r & 127;
    const float* s = src + (size_t)mat * 16384;
    dst[i] = __floats2half2_rn(s[(2 * k2) * 128 + c], s[(2 * k2 + 1) * 128 + c]);
}

// Filter tables, wave = 4 rows x 128 channels (lane = channel). [R14 winner]
__global__ __launch_bounds__(256, 4) void k_tab2(
    const float* __restrict__ mlp1_w, const float* __restrict__ mlp1_b,
    const float* __restrict__ mlp2_w, const float* __restrict__ mlp2_b,
    float* __restrict__ ftab)
{
    __shared__ float tls[4 * 4 * TSTRIDE];
    const int w = threadIdx.x >> 6;
    const int lane = threadIdx.x & 63;
    const int gr = blockIdx.x * 16 + w * 4;
    const int layer = gr >> 11;
    const int r0 = gr & (TROWS - 1);
    const float* W1 = mlp1_w + (size_t)layer * NG * FILT;
    const float* B1 = mlp1_b + (size_t)layer * FILT;
    const float* W2 = mlp2_w + (size_t)layer * FILT * FILT;
    const float* B2 = mlp2_b + (size_t)layer * FILT;
    float* tp = &tls[w * 4 * TSTRIDE];
    float acc1[4][2];
    {
        float ba = B1[lane], bb = B1[lane + 64];
        #pragma unroll
        for (int j = 0; j < 4; ++j) { acc1[j][0] = ba; acc1[j][1] = bb; }
    }
    for (int k = 0; k < NG; ++k) {
        float wa = W1[k * FILT + lane];
        float wb = W1[k * FILT + lane + 64];
        #pragma unroll
        for (int j = 0; j < 4; ++j) {
            float dd = (float)(r0 + j) * DSTEP - 0.2f * (float)k;
            float g = __expf(-12.5f * dd * dd);
            acc1[j][0] = fmaf(g, wa, acc1[j][0]);
            acc1[j][1] = fmaf(g, wb, acc1[j][1]);
        }
    }
    #pragma unroll
    for (int j = 0; j < 4; ++j) {
        tp[j * TSTRIDE + lane] = ssp(acc1[j][0]);
        tp[j * TSTRIDE + lane + 64] = ssp(acc1[j][1]);
    }
    __syncthreads();
    float acc2[4][2];
    {
        float ba = B2[lane], bb = B2[lane + 64];
        #pragma unroll
        for (int j = 0; j < 4; ++j) { acc2[j][0] = ba; acc2[j][1] = bb; }
    }
    #pragma unroll 4
    for (int k = 0; k < FILT; k += 2) {
        float w0a = W2[k * FILT + lane];
        float w0b = W2[k * FILT + lane + 64];
        float w1a = W2[(k + 1) * FILT + lane];
        float w1b = W2[(k + 1) * FILT + lane + 64];
        #pragma unroll
        for (int j = 0; j < 4; ++j) {
            float2 t = *(float2*)&tp[j * TSTRIDE + k];
            acc2[j][0] = fmaf(t.x, w0a, fmaf(t.y, w1a, acc2[j][0]));
            acc2[j][1] = fmaf(t.x, w0b, fmaf(t.y, w1b, acc2[j][1]));
        }
    }
    #pragma unroll
    for (int j = 0; j < 4; ++j) {
        float d = (float)(r0 + j) * DSTEP;
        float C = 0.5f * (__cosf(d * 0.31415926535f) + 1.0f);
        float* out = ftab + (size_t)layer * TROWS * FILT + (size_t)(r0 + j) * FILT;
        out[lane] = acc2[j][0] * C;
        out[lane + 64] = acc2[j][1] * C;
    }
}

// Half-wave-paired edge aggregation; xh gathered in FP16. [R19 winner]
__global__ __launch_bounds__(256, 7) void k_edge9(
    const int2* __restrict__ meta, const int* __restrict__ rowptr,
    const __half* __restrict__ xh, const float* __restrict__ tab,
    float* __restrict__ agg)
{
    const int row = blockIdx.x * 4 + (threadIdx.x >> 6);
    const int lane = threadIdx.x & 63;
    const int half = lane >> 5;
    const int c4 = (lane & 31) * 4;
    const int es = rowptr[row], ee = rowptr[row + 1];
    float4 acc = make_float4(0.f, 0.f, 0.f, 0.f);
    if (es < ee) {
        int2 mcur[EU];
        #pragma unroll
        for (int u = 0; u < EU; ++u)
            mcur[u] = meta[min(es + 2 * u + half, ee - 1)];
        for (int e = es; e < ee; e += 2 * EU) {
            const int en = e + 2 * EU;
            int2 mnext[EU];
            if (en < ee) {
                #pragma unroll
                for (int u = 0; u < EU; ++u)
                    mnext[u] = meta[min(en + 2 * u + half, ee - 1)];
            }
            float4 t0[EU], t1[EU];
            float2 xr[EU];
            float f[EU], sc[EU];
            #pragma unroll
            for (int u = 0; u < EU; ++u) {
                sc[u] = (e + 2 * u + half < ee) ? 1.f : 0.f;
                float d = __int_as_float(mcur[u].y);
                float uu = d * INV_DSTEP;
                int i0 = min((int)uu, TROWS - 2);
                f[u] = uu - (float)i0;
                t0[u] = *(const float4*)&tab[(size_t)i0 * FILT + c4];
                t1[u] = *(const float4*)&tab[(size_t)(i0 + 1) * FILT + c4];
                xr[u] = *(const float2*)&xh[(size_t)mcur[u].x * FILT + c4]; // 4 halves
            }
            #pragma unroll
            for (int u = 0; u < EU; ++u) {
                __half2 h01 = *reinterpret_cast<__half2*>(&xr[u].x);
                __half2 h23 = *reinterpret_cast<__half2*>(&xr[u].y);
                float2 x01 = __half22float2(h01);
                float2 x23 = __half22float2(h23);
                acc.x = fmaf(fmaf(f[u], t1[u].x - t0[u].x, t0[u].x) * sc[u], x01.x, acc.x);
                acc.y = fmaf(fmaf(f[u], t1[u].y - t0[u].y, t0[u].y) * sc[u], x01.y, acc.y);
                acc.z = fmaf(fmaf(f[u], t1[u].z - t0[u].z, t0[u].z) * sc[u], x23.x, acc.z);
                acc.w = fmaf(fmaf(f[u], t1[u].w - t0[u].w, t0[u].w) * sc[u], x23.y, acc.w);
            }
            #pragma unroll
            for (int u = 0; u < EU; ++u) mcur[u] = mnext[u];
        }
        acc.x += __shfl_xor(acc.x, 32, 64);
        acc.y += __shfl_xor(acc.y, 32, 64);
        acc.z += __shfl_xor(acc.z, 32, 64);
        acc.w += __shfl_xor(acc.w, 32, 64);
    }
    if (half == 0)
        *(float4*)&agg[(size_t)row * FILT + c4] = acc;
}

// ---------------------------------------------------------------------------
// Node GEMMs: R16/R18 structure, W in fp16 k-pair packing -- one dword load
// per stream covers TWO k-steps (half the VMEM instrs and bytes).
// ---------------------------------------------------------------------------
__global__ __launch_bounds__(256, 4) void k_gemm0(const float* __restrict__ X,
                                                  const __half2* __restrict__ Wh,
                                                  __half* __restrict__ Y) {
    const int w = threadIdx.x >> 6;
    const int lane = threadIdx.x & 63;
    const int nb = __builtin_amdgcn_readfirstlane(blockIdx.x * 16 + w * 4);
    const float* x0 = X + (size_t)nb * 128;
    const float* x1 = x0 + 128;
    const float* x2 = x1 + 128;
    const float* x3 = x2 + 128;
    float acc[4][2];
    #pragma unroll
    for (int j = 0; j < 4; ++j) { acc[j][0] = 0.f; acc[j][1] = 0.f; }
    #pragma unroll 4
    for (int k2 = 0; k2 < 64; ++k2) {
        float2 wa = __half22float2(Wh[k2 * 128 + lane]);
        float2 wb = __half22float2(Wh[k2 * 128 + lane + 64]);
        float a00 = x0[2 * k2], a01 = x0[2 * k2 + 1];
        float a10 = x1[2 * k2], a11 = x1[2 * k2 + 1];
        float a20 = x2[2 * k2], a21 = x2[2 * k2 + 1];
        float a30 = x3[2 * k2], a31 = x3[2 * k2 + 1];
        acc[0][0] = fmaf(a00, wa.x, fmaf(a01, wa.y, acc[0][0]));
        acc[0][1] = fmaf(a00, wb.x, fmaf(a01, wb.y, acc[0][1]));
        acc[1][0] = fmaf(a10, wa.x, fmaf(a11, wa.y, acc[1][0]));
        acc[1][1] = fmaf(a10, wb.x, fmaf(a11, wb.y, acc[1][1]));
        acc[2][0] = fmaf(a20, wa.x, fmaf(a21, wa.y, acc[2][0]));
        acc[2][1] = fmaf(a20, wb.x, fmaf(a21, wb.y, acc[2][1]));
        acc[3][0] = fmaf(a30, wa.x, fmaf(a31, wa.y, acc[3][0]));
        acc[3][1] = fmaf(a30, wb.x, fmaf(a31, wb.y, acc[3][1]));
    }
    #pragma unroll
    for (int j = 0; j < 4; ++j) {
        size_t ro = (size_t)(nb + j) * 128;
        Y[ro + lane] = __float2half_rn(acc[j][0]);
        Y[ro + lane + 64] = __float2half_rn(acc[j][1]);
    }
}

template<bool RESID, bool G3>
__global__ __launch_bounds__(256, 4) void k_node5(
    const float* __restrict__ X,
    const __half2* __restrict__ W1h, const float* __restrict__ B1,
    const __half2* __restrict__ W2h, const float* __restrict__ B2,
    const float* __restrict__ Hin, float* __restrict__ Hout,
    const __half2* __restrict__ W3h, __half* __restrict__ XHout)
{
    __shared__ float tls[4 * 4 * TSTRIDE];
    const int w = threadIdx.x >> 6;
    const int lane = threadIdx.x & 63;
    const int nb = __builtin_amdgcn_readfirstlane(blockIdx.x * 16 + w * 4);
    float* tp = &tls[w * 4 * TSTRIDE];
    const float* x0 = X + (size_t)nb * 128;
    const float* x1 = x0 + 128;
    const float* x2 = x1 + 128;
    const float* x3 = x2 + 128;
    // ---- GEMM1: t = ssp(X @ W1 + B1) ----
    float acc1[4][2];
    {
        float ba = B1[lane], bb = B1[lane + 64];
        #pragma unroll
        for (int j = 0; j < 4; ++j) { acc1[j][0] = ba; acc1[j][1] = bb; }
    }
    #pragma unroll 4
    for (int k2 = 0; k2 < 64; ++k2) {
        float2 wa = __half22float2(W1h[k2 * 128 + lane]);
        float2 wb = __half22float2(W1h[k2 * 128 + lane + 64]);
        float a00 = x0[2 * k2], a01 = x0[2 * k2 + 1];
        float a10 = x1[2 * k2], a11 = x1[2 * k2 + 1];
        float a20 = x2[2 * k2], a21 = x2[2 * k2 + 1];
        float a30 = x3[2 * k2], a31 = x3[2 * k2 + 1];
        acc1[0][0] = fmaf(a00, wa.x, fmaf(a01, wa.y, acc1[0][0]));
        acc1[0][1] = fmaf(a00, wb.x, fmaf(a01, wb.y, acc1[0][1]));
        acc1[1][0] = fmaf(a10, wa.x, fmaf(a11, wa.y, acc1[1][0]));
        acc1[1][1] = fmaf(a10, wb.x, fmaf(a11, wb.y, acc1[1][1]));
        acc1[2][0] = fmaf(a20, wa.x, fmaf(a21, wa.y, acc1[2][0]));
        acc1[2][1] = fmaf(a20, wb.x, fmaf(a21, wb.y, acc1[2][1]));
        acc1[3][0] = fmaf(a30, wa.x, fmaf(a31, wa.y, acc1[3][0]));
        acc1[3][1] = fmaf(a30, wb.x, fmaf(a31, wb.y, acc1[3][1]));
    }
    #pragma unroll
    for (int j = 0; j < 4; ++j) {
        tp[j * TSTRIDE + lane] = ssp(acc1[j][0]);
        tp[j * TSTRIDE + lane + 64] = ssp(acc1[j][1]);
    }
    __syncthreads();
    // ---- GEMM2: out = t @ W2 + B2 (+Hin) ----
    float acc2[4][2];
    {
        float ba = B2[lane], bb = B2[lane + 64];
        #pragma unroll
        for (int j = 0; j < 4; ++j) { acc2[j][0] = ba; acc2[j][1] = bb; }
    }
    #pragma unroll 4
    for (int k2 = 0; k2 < 64; ++k2) {
        float2 wa = __half22float2(W2h[k2 * 128 + lane]);
        float2 wb = __half22float2(W2h[k2 * 128 + lane + 64]);
        #pragma unroll
        for (int j = 0; j < 4; ++j) {
            float2 t = *(float2*)&tp[j * TSTRIDE + 2 * k2];
            acc2[j][0] = fmaf(t.x, wa.x, fmaf(t.y, wa.y, acc2[j][0]));
            acc2[j][1] = fmaf(t.x, wb.x, fmaf(t.y, wb.y, acc2[j][1]));
        }
    }
    #pragma unroll
    for (int j = 0; j < 4; ++j) {
        size_t ro = (size_t)(nb + j) * 128;
        if (RESID) {
            acc2[j][0] += Hin[ro + lane];
            acc2[j][1] += Hin[ro + lane + 64];
        }
        Hout[ro + lane] = acc2[j][0];
        Hout[ro + lane + 64] = acc2[j][1];
    }
    // ---- GEMM3: xh_next = out @ W3 (fp16 out) ----
    if (G3) {
        __syncthreads();
        #pragma unroll
        for (int j = 0; j < 4; ++j) {
            tp[j * TSTRIDE + lane] = acc2[j][0];
            tp[j * TSTRIDE + lane + 64] = acc2[j][1];
        }
        __syncthreads();
        float acc3[4][2];
        #pragma unroll
        for (int j = 0; j < 4; ++j) { acc3[j][0] = 0.f; acc3[j][1] = 0.f; }
        #pragma unroll 4
        for (int k2 = 0; k2 < 64; ++k2) {
            float2 wa = __half22float2(W3h[k2 * 128 + lane]);
            float2 wb = __half22float2(W3h[k2 * 128 + lane + 64]);
            #pragma unroll
            for (int j = 0; j < 4; ++j) {
                float2 t = *(float2*)&tp[j * TSTRIDE + 2 * k2];
                acc3[j][0] = fmaf(t.x, wa.x, fmaf(t.y, wa.y, acc3[j][0]));
                acc3[j][1] = fmaf(t.x, wb.x, fmaf(t.y, wb.y, acc3[j][1]));
            }
        }
        #pragma unroll
        for (int j = 0; j < 4; ++j) {
            size_t ro = (size_t)(nb + j) * 128;
            XHout[ro + lane] = __float2half_rn(acc3[j][0]);
            XHout[ro + lane + 64] = __float2half_rn(acc3[j][1]);
        }
    }
}

// Partial-sum pooling using sortedness of batch.
__global__ __launch_bounds__(128) void k_pool2(const float* __restrict__ x,
                                               const int* __restrict__ batch,
                                               float* __restrict__ gsum) {
    const int c = threadIdx.x;
    const int n0 = blockIdx.x * 64;
    float acc = 0.f;
    int cur = batch[n0];
    for (int i = 0; i < 64; ++i) {
        int g = batch[n0 + i];
        float v = x[(size_t)(n0 + i) * 128 + c];
        if (g != cur) {
            atomicAdd(&gsum[cur * 128 + c], acc);
            acc = 0.f;
            cur = g;
        }
        acc += v;
    }
    atomicAdd(&gsum[cur * 128 + c], acc);
}

__global__ void k_div(const float* __restrict__ gsum, const int* __restrict__ batch,
                      float* __restrict__ out) {
    int g = blockIdx.x;
    int c = threadIdx.x;
    int a = 0, b = N_NODES;
    while (a < b) { int m = (a + b) >> 1; if (batch[m] < g) a = m + 1; else b = m; }
    int lo = a;
    b = N_NODES;
    while (a < b) { int m = (a + b) >> 1; if (batch[m] < g + 1) a = m + 1; else b = m; }
    int cnt = a - lo;
    out[g * 128 + c] = gsum[g * 128 + c] / fmaxf((float)cnt, 1.0f);
}

extern "C" void kernel_launch(void* const* d_in, const int* in_sizes, int n_in,
                              void* d_out, int out_size, void* d_ws, size_t ws_size,
                              hipStream_t stream) {
    const int*   z       = (const int*)  d_in[0];
    const float* pos     = (const float*)d_in[1];
    const int*   batch   = (const int*)  d_in[2];
    const int*   ei      = (const int*)  d_in[3];
    const float* emb     = (const float*)d_in[4];
    const float* mlp1_w  = (const float*)d_in[5];
    const float* mlp1_b  = (const float*)d_in[6];
    const float* mlp2_w  = (const float*)d_in[7];
    const float* mlp2_b  = (const float*)d_in[8];
    const float* cl1_w   = (const float*)d_in[9];
    const float* cl2_w   = (const float*)d_in[10];
    const float* cl2_b   = (const float*)d_in[11];
    const float* lin_w   = (const float*)d_in[12];
    const float* lin_b   = (const float*)d_in[13];
    const float* out1_w  = (const float*)d_in[14];
    const float* out1_b  = (const float*)d_in[15];
    const float* out2_w  = (const float*)d_in[16];
    const float* out2_b  = (const float*)d_in[17];

    float* ws     = (float*)d_ws;
    float* h      = ws;
    float* xhf    = h    + (size_t)N_NODES * HID;
    __half* xh    = (__half*)xhf;                   // N_NODES*HID halves (4 MB)
    float* agg    = xhf  + (size_t)N_NODES * HID;
    int2*  meta   = (int2*)(agg + (size_t)N_NODES * HID);
    int*   cnt    = (int*)(meta + N_EDGES);
    int*   rowptr = cnt + N_NODES;
    int*   wo     = rowptr + N_NODES + 1;
    float* gsum   = (float*)(wo + N_NODES);            // 64*128
    float* ftab   = gsum + N_GRAPHS * 128;             // NL*TROWS*FILT floats
    __half2* whb  = (__half2*)(ftab + (size_t)NL * TROWS * FILT); // 20*8192 half2

    hipMemsetAsync(cnt, 0, N_NODES * sizeof(int), stream);
    hipMemsetAsync(gsum, 0, N_GRAPHS * 128 * sizeof(float), stream);
    k_embed<<<N_NODES * HID / 256, 256, 0, stream>>>(z, emb, h);
    k_hist<<<N_EDGES / 256, 256, 0, stream>>>(ei, cnt);
    k_scan<<<1, 1024, 0, stream>>>(cnt, rowptr, wo);
    k_scatter<<<N_EDGES / 256, 256, 0, stream>>>(ei, pos, wo, meta);
    k_tab2<<<NL * TROWS / 16, 256, 0, stream>>>(mlp1_w, mlp1_b, mlp2_w, mlp2_b, ftab);
    // pack weights to fp16 k-pairs: [0..5]=cl1, [6..11]=cl2, [12..17]=lin, 18=out1, 19=out2
    k_wcvt<<<(6 * 8192 + 255) / 256, 256, 0, stream>>>(cl1_w, whb, 6 * 8192);
    k_wcvt<<<(6 * 8192 + 255) / 256, 256, 0, stream>>>(cl2_w, whb + 6 * 8192, 6 * 8192);
    k_wcvt<<<(6 * 8192 + 255) / 256, 256, 0, stream>>>(lin_w, whb + 12 * 8192, 6 * 8192);
    k_wcvt<<<(8192 + 255) / 256, 256, 0, stream>>>(out1_w, whb + 18 * 8192, 8192);
    k_wcvt<<<(8192 + 255) / 256, 256, 0, stream>>>(out2_w, whb + 19 * 8192, 8192);

    k_gemm0<<<N_NODES / 16, 256, 0, stream>>>(h, whb, xh);
    for (int i = 0; i < NL; ++i) {
        k_edge9<<<N_NODES / 4, 256, 0, stream>>>(
            meta, rowptr, xh, ftab + (size_t)i * TROWS * FILT, agg);
        if (i < NL - 1) {
            k_node5<true, true><<<N_NODES / 16, 256, 0, stream>>>(
                agg, whb + (size_t)(6 + i) * 8192, cl2_b + (size_t)i * HID,
                whb + (size_t)(12 + i) * 8192, lin_b + (size_t)i * HID,
                h, h, whb + (size_t)(i + 1) * 8192, xh);
        } else {
            k_node5<true, false><<<N_NODES / 16, 256, 0, stream>>>(
                agg, whb + (size_t)(6 + i) * 8192, cl2_b + (size_t)i * HID,
                whb + (size_t)(12 + i) * 8192, lin_b + (size_t)i * HID,
                h, h, nullptr, nullptr);
        }
    }
    // final MLP (fp32 out into agg), then pool
    k_node5<false, false><<<N_NODES / 16, 256, 0, stream>>>(
        h, whb + 18 * 8192, out1_b, whb + 19 * 8192, out2_b,
        nullptr, agg, nullptr, nullptr);
    k_pool2<<<N_NODES / 64, 128, 0, stream>>>(agg, batch, gsum);
    k_div<<<N_GRAPHS, 128, 0, stream>>>(gsum, batch, (float*)d_out);
}

// Round 21
// 576.778 us; speedup vs baseline: 1.0608x; 1.0608x over previous
//
#include <hip/hip_runtime.h>
#include <hip/hip_fp16.h>
#include <math.h>

#define N_NODES 16384
#define N_EDGES 524288
#define N_GRAPHS 64
#define HID 128
#define FILT 128
#define NG 51
#define NL 6
#define TROWS 2048   // filter-table resolution
#define DMAX 8.66025404f          // 5*sqrt(3), max possible distance
#define DSTEP (DMAX / (TROWS - 1))
#define INV_DSTEP ((TROWS - 1) / DMAX)
#define EU 3         // edge-pair unroll (6 edges in flight)
#define TSTRIDE 132  // LDS row stride (pad; keeps float2 8B-aligned)

__device__ __forceinline__ float ssp(float x) {
    float sp = (x > 20.0f) ? x : log1pf(__expf(x));
    return sp - 0.6931471805599453f;
}

__global__ void k_embed(const int* __restrict__ z, const float* __restrict__ emb,
                        float* __restrict__ h) {
    int i = blockIdx.x * blockDim.x + threadIdx.x;
    int n = i >> 7, c = i & 127;
    h[i] = emb[z[n] * HID + c];
}

__global__ void k_hist(const int* __restrict__ ei, int* __restrict__ cnt) {
    int e = blockIdx.x * blockDim.x + threadIdx.x;
    if (e < N_EDGES) atomicAdd(&cnt[ei[e]], 1);
}

__global__ __launch_bounds__(1024) void k_scan(const int* __restrict__ cnt,
                                               int* __restrict__ rowptr,
                                               int* __restrict__ wo) {
    __shared__ int sums[1024];
    int t = threadIdx.x;
    int loc[16];
    int s = 0;
    #pragma unroll
    for (int i = 0; i < 16; ++i) { loc[i] = cnt[t * 16 + i]; s += loc[i]; }
    sums[t] = s;
    __syncthreads();
    for (int off = 1; off < 1024; off <<= 1) {
        int v = sums[t];
        int u = (t >= off) ? sums[t - off] : 0;
        __syncthreads();
        sums[t] = v + u;
        __syncthreads();
    }
    int ex = sums[t] - s;
    #pragma unroll
    for (int i = 0; i < 16; ++i) {
        rowptr[t * 16 + i] = ex;
        wo[t * 16 + i] = ex;
        ex += loc[i];
    }
    if (t == 1023) rowptr[16384] = ex;
}

// scatter into CSR order: meta.x = col, meta.y = ew bits
__global__ void k_scatter(const int* __restrict__ ei, const float* __restrict__ pos,
                          int* __restrict__ wo, int2* __restrict__ meta) {
    int e = blockIdx.x * blockDim.x + threadIdx.x;
    if (e >= N_EDGES) return;
    int r = ei[e], c = ei[N_EDGES + e];
    int p = atomicAdd(&wo[r], 1);
    float dx = pos[r * 3 + 0] - pos[c * 3 + 0];
    float dy = pos[r * 3 + 1] - pos[c * 3 + 1];
    float dz = pos[r * 3 + 2] - pos[c * 3 + 2];
    float ew = sqrtf(dx * dx + dy * dy + dz * dz);
    meta[p] = make_int2(c, __float_as_int(ew));
}

// Filter tables, wave = 4 rows x 128 channels (lane = channel); fp16 output.
__global__ __launch_bounds__(256, 4) void k_tab2(
    const float* __restrict__ mlp1_w, const float* __restrict__ mlp1_b,
    const float* __restrict__ mlp2_w, const float* __restrict__ mlp2_b,
    __half* __restrict__ ftab)
{
    __shared__ float tls[4 * 4 * TSTRIDE];
    const int w = threadIdx.x >> 6;
    const int lane = threadIdx.x & 63;
    const int gr = blockIdx.x * 16 + w * 4;
    const int layer = gr >> 11;
    const int r0 = gr & (TROWS - 1);
    const float* W1 = mlp1_w + (size_t)layer * NG * FILT;
    const float* B1 = mlp1_b + (size_t)layer * FILT;
    const float* W2 = mlp2_w + (size_t)layer * FILT * FILT;
    const float* B2 = mlp2_b + (size_t)layer * FILT;
    float* tp = &tls[w * 4 * TSTRIDE];
    float acc1[4][2];
    {
        float ba = B1[lane], bb = B1[lane + 64];
        #pragma unroll
        for (int j = 0; j < 4; ++j) { acc1[j][0] = ba; acc1[j][1] = bb; }
    }
    for (int k = 0; k < NG; ++k) {
        float wa = W1[k * FILT + lane];
        float wb = W1[k * FILT + lane + 64];
        #pragma unroll
        for (int j = 0; j < 4; ++j) {
            float dd = (float)(r0 + j) * DSTEP - 0.2f * (float)k;
            float g = __expf(-12.5f * dd * dd);
            acc1[j][0] = fmaf(g, wa, acc1[j][0]);
            acc1[j][1] = fmaf(g, wb, acc1[j][1]);
        }
    }
    #pragma unroll
    for (int j = 0; j < 4; ++j) {
        tp[j * TSTRIDE + lane] = ssp(acc1[j][0]);
        tp[j * TSTRIDE + lane + 64] = ssp(acc1[j][1]);
    }
    __syncthreads();
    float acc2[4][2];
    {
        float ba = B2[lane], bb = B2[lane + 64];
        #pragma unroll
        for (int j = 0; j < 4; ++j) { acc2[j][0] = ba; acc2[j][1] = bb; }
    }
    #pragma unroll 4
    for (int k = 0; k < FILT; k += 2) {
        float w0a = W2[k * FILT + lane];
        float w0b = W2[k * FILT + lane + 64];
        float w1a = W2[(k + 1) * FILT + lane];
        float w1b = W2[(k + 1) * FILT + lane + 64];
        #pragma unroll
        for (int j = 0; j < 4; ++j) {
            float2 t = *(float2*)&tp[j * TSTRIDE + k];
            acc2[j][0] = fmaf(t.x, w0a, fmaf(t.y, w1a, acc2[j][0]));
            acc2[j][1] = fmaf(t.x, w0b, fmaf(t.y, w1b, acc2[j][1]));
        }
    }
    #pragma unroll
    for (int j = 0; j < 4; ++j) {
        float d = (float)(r0 + j) * DSTEP;
        float C = 0.5f * (__cosf(d * 0.31415926535f) + 1.0f);
        __half* out = ftab + (size_t)layer * TROWS * FILT + (size_t)(r0 + j) * FILT;
        out[lane] = __float2half_rn(acc2[j][0] * C);
        out[lane + 64] = __float2half_rn(acc2[j][1] * C);
    }
}

// Half-wave-paired edge aggregation; xh AND tab in FP16 (per-edge VMEM bytes
// 40 -> 24; table footprint 512 KB/layer -> better per-XCD L2 residency).
__global__ __launch_bounds__(256, 7) void k_edge9(
    const int2* __restrict__ meta, const int* __restrict__ rowptr,
    const __half* __restrict__ xh, const __half* __restrict__ tab,
    float* __restrict__ agg)
{
    const int row = blockIdx.x * 4 + (threadIdx.x >> 6);
    const int lane = threadIdx.x & 63;
    const int half = lane >> 5;
    const int c4 = (lane & 31) * 4;
    const int es = rowptr[row], ee = rowptr[row + 1];
    float4 acc = make_float4(0.f, 0.f, 0.f, 0.f);
    if (es < ee) {
        int2 mcur[EU];
        #pragma unroll
        for (int u = 0; u < EU; ++u)
            mcur[u] = meta[min(es + 2 * u + half, ee - 1)];
        for (int e = es; e < ee; e += 2 * EU) {
            const int en = e + 2 * EU;
            int2 mnext[EU];
            if (en < ee) {
                #pragma unroll
                for (int u = 0; u < EU; ++u)
                    mnext[u] = meta[min(en + 2 * u + half, ee - 1)];
            }
            float2 t0h[EU], t1h[EU], xr[EU];
            float f[EU], sc[EU];
            #pragma unroll
            for (int u = 0; u < EU; ++u) {
                sc[u] = (e + 2 * u + half < ee) ? 1.f : 0.f;
                float d = __int_as_float(mcur[u].y);
                float uu = d * INV_DSTEP;
                int i0 = min((int)uu, TROWS - 2);
                f[u] = uu - (float)i0;
                t0h[u] = *(const float2*)&tab[(size_t)i0 * FILT + c4];       // 4 halves
                t1h[u] = *(const float2*)&tab[(size_t)(i0 + 1) * FILT + c4]; // 4 halves
                xr[u]  = *(const float2*)&xh[(size_t)mcur[u].x * FILT + c4]; // 4 halves
            }
            #pragma unroll
            for (int u = 0; u < EU; ++u) {
                float2 T0a = __half22float2(*reinterpret_cast<__half2*>(&t0h[u].x));
                float2 T0b = __half22float2(*reinterpret_cast<__half2*>(&t0h[u].y));
                float2 T1a = __half22float2(*reinterpret_cast<__half2*>(&t1h[u].x));
                float2 T1b = __half22float2(*reinterpret_cast<__half2*>(&t1h[u].y));
                float2 x01 = __half22float2(*reinterpret_cast<__half2*>(&xr[u].x));
                float2 x23 = __half22float2(*reinterpret_cast<__half2*>(&xr[u].y));
                acc.x = fmaf(fmaf(f[u], T1a.x - T0a.x, T0a.x) * sc[u], x01.x, acc.x);
                acc.y = fmaf(fmaf(f[u], T1a.y - T0a.y, T0a.y) * sc[u], x01.y, acc.y);
                acc.z = fmaf(fmaf(f[u], T1b.x - T0b.x, T0b.x) * sc[u], x23.x, acc.z);
                acc.w = fmaf(fmaf(f[u], T1b.y - T0b.y, T0b.y) * sc[u], x23.y, acc.w);
            }
            #pragma unroll
            for (int u = 0; u < EU; ++u) mcur[u] = mnext[u];
        }
        acc.x += __shfl_xor(acc.x, 32, 64);
        acc.y += __shfl_xor(acc.y, 32, 64);
        acc.z += __shfl_xor(acc.z, 32, 64);
        acc.w += __shfl_xor(acc.w, 32, 64);
    }
    if (half == 0)
        *(float4*)&agg[(size_t)row * FILT + c4] = acc;
}

// ---------------------------------------------------------------------------
// Node GEMMs [R13/R16/R19 winner, fp32 W]: wave = 4 nodes x 128 channels.
// ---------------------------------------------------------------------------
__global__ __launch_bounds__(256, 4) void k_gemm0(const float* __restrict__ X,
                                                  const float* __restrict__ W,
                                                  __half* __restrict__ Y) {
    const int w = threadIdx.x >> 6;
    const int lane = threadIdx.x & 63;
    const int nb = __builtin_amdgcn_readfirstlane(blockIdx.x * 16 + w * 4);
    const float* x0 = X + (size_t)nb * 128;
    const float* x1 = x0 + 128;
    const float* x2 = x1 + 128;
    const float* x3 = x2 + 128;
    float acc[4][2];
    #pragma unroll
    for (int j = 0; j < 4; ++j) { acc[j][0] = 0.f; acc[j][1] = 0.f; }
    #pragma unroll 8
    for (int k = 0; k < 128; ++k) {
        float wa = W[k * 128 + lane];
        float wb = W[k * 128 + lane + 64];
        float a0 = x0[k], a1 = x1[k], a2 = x2[k], a3 = x3[k];
        acc[0][0] = fmaf(a0, wa, acc[0][0]); acc[0][1] = fmaf(a0, wb, acc[0][1]);
        acc[1][0] = fmaf(a1, wa, acc[1][0]); acc[1][1] = fmaf(a1, wb, acc[1][1]);
        acc[2][0] = fmaf(a2, wa, acc[2][0]); acc[2][1] = fmaf(a2, wb, acc[2][1]);
        acc[3][0] = fmaf(a3, wa, acc[3][0]); acc[3][1] = fmaf(a3, wb, acc[3][1]);
    }
    #pragma unroll
    for (int j = 0; j < 4; ++j) {
        size_t ro = (size_t)(nb + j) * 128;
        Y[ro + lane] = __float2half_rn(acc[j][0]);
        Y[ro + lane + 64] = __float2half_rn(acc[j][1]);
    }
}

template<bool RESID, bool G3>
__global__ __launch_bounds__(256, 4) void k_node5(
    const float* __restrict__ X,
    const float* __restrict__ W1, const float* __restrict__ B1,
    const float* __restrict__ W2, const float* __restrict__ B2,
    const float* __restrict__ Hin, float* __restrict__ Hout,
    const float* __restrict__ W3, __half* __restrict__ XHout)
{
    __shared__ float tls[4 * 4 * TSTRIDE];
    const int w = threadIdx.x >> 6;
    const int lane = threadIdx.x & 63;
    const int nb = __builtin_amdgcn_readfirstlane(blockIdx.x * 16 + w * 4);
    float* tp = &tls[w * 4 * TSTRIDE];
    const float* x0 = X + (size_t)nb * 128;
    const float* x1 = x0 + 128;
    const float* x2 = x1 + 128;
    const float* x3 = x2 + 128;
    // ---- GEMM1: t = ssp(X @ W1 + B1) ----
    float acc1[4][2];
    {
        float ba = B1[lane], bb = B1[lane + 64];
        #pragma unroll
        for (int j = 0; j < 4; ++j) { acc1[j][0] = ba; acc1[j][1] = bb; }
    }
    #pragma unroll 8
    for (int k = 0; k < 128; ++k) {
        float wa = W1[k * 128 + lane];
        float wb = W1[k * 128 + lane + 64];
        float a0 = x0[k], a1 = x1[k], a2 = x2[k], a3 = x3[k];
        acc1[0][0] = fmaf(a0, wa, acc1[0][0]); acc1[0][1] = fmaf(a0, wb, acc1[0][1]);
        acc1[1][0] = fmaf(a1, wa, acc1[1][0]); acc1[1][1] = fmaf(a1, wb, acc1[1][1]);
        acc1[2][0] = fmaf(a2, wa, acc1[2][0]); acc1[2][1] = fmaf(a2, wb, acc1[2][1]);
        acc1[3][0] = fmaf(a3, wa, acc1[3][0]); acc1[3][1] = fmaf(a3, wb, acc1[3][1]);
    }
    #pragma unroll
    for (int j = 0; j < 4; ++j) {
        tp[j * TSTRIDE + lane] = ssp(acc1[j][0]);
        tp[j * TSTRIDE + lane + 64] = ssp(acc1[j][1]);
    }
    __syncthreads();
    // ---- GEMM2: out = t @ W2 + B2 (+Hin) ----
    float acc2[4][2];
    {
        float ba = B2[lane], bb = B2[lane + 64];
        #pragma unroll
        for (int j = 0; j < 4; ++j) { acc2[j][0] = ba; acc2[j][1] = bb; }
    }
    #pragma unroll 4
    for (int k = 0; k < 128; k += 2) {
        float w0a = W2[k * 128 + lane];
        float w0b = W2[k * 128 + lane + 64];
        float w1a = W2[(k + 1) * 128 + lane];
        float w1b = W2[(k + 1) * 128 + lane + 64];
        #pragma unroll
        for (int j = 0; j < 4; ++j) {
            float2 t = *(float2*)&tp[j * TSTRIDE + k];
            acc2[j][0] = fmaf(t.x, w0a, fmaf(t.y, w1a, acc2[j][0]));
            acc2[j][1] = fmaf(t.x, w0b, fmaf(t.y, w1b, acc2[j][1]));
        }
    }
    #pragma unroll
    for (int j = 0; j < 4; ++j) {
        size_t ro = (size_t)(nb + j) * 128;
        if (RESID) {
            acc2[j][0] += Hin[ro + lane];
            acc2[j][1] += Hin[ro + lane + 64];
        }
        Hout[ro + lane] = acc2[j][0];
        Hout[ro + lane + 64] = acc2[j][1];
    }
    // ---- GEMM3: xh_next = out @ W3 (fp16 out) ----
    if (G3) {
        __syncthreads();
        #pragma unroll
        for (int j = 0; j < 4; ++j) {
            tp[j * TSTRIDE + lane] = acc2[j][0];
            tp[j * TSTRIDE + lane + 64] = acc2[j][1];
        }
        __syncthreads();
        float acc3[4][2];
        #pragma unroll
        for (int j = 0; j < 4; ++j) { acc3[j][0] = 0.f; acc3[j][1] = 0.f; }
        #pragma unroll 4
        for (int k = 0; k < 128; k += 2) {
            float w0a = W3[k * 128 + lane];
            float w0b = W3[k * 128 + lane + 64];
            float w1a = W3[(k + 1) * 128 + lane];
            float w1b = W3[(k + 1) * 128 + lane + 64];
            #pragma unroll
            for (int j = 0; j < 4; ++j) {
                float2 t = *(float2*)&tp[j * TSTRIDE + k];
                acc3[j][0] = fmaf(t.x, w0a, fmaf(t.y, w1a, acc3[j][0]));
                acc3[j][1] = fmaf(t.x, w0b, fmaf(t.y, w1b, acc3[j][1]));
            }
        }
        #pragma unroll
        for (int j = 0; j < 4; ++j) {
            size_t ro = (size_t)(nb + j) * 128;
            XHout[ro + lane] = __float2half_rn(acc3[j][0]);
            XHout[ro + lane + 64] = __float2half_rn(acc3[j][1]);
        }
    }
}

// Partial-sum pooling using sortedness of batch.
__global__ __launch_bounds__(128) void k_pool2(const float* __restrict__ x,
                                               const int* __restrict__ batch,
                                               float* __restrict__ gsum) {
    const int c = threadIdx.x;
    const int n0 = blockIdx.x * 64;
    float acc = 0.f;
    int cur = batch[n0];
    for (int i = 0; i < 64; ++i) {
        int g = batch[n0 + i];
        float v = x[(size_t)(n0 + i) * 128 + c];
        if (g != cur) {
            atomicAdd(&gsum[cur * 128 + c], acc);
            acc = 0.f;
            cur = g;
        }
        acc += v;
    }
    atomicAdd(&gsum[cur * 128 + c], acc);
}

__global__ void k_div(const float* __restrict__ gsum, const int* __restrict__ batch,
                      float* __restrict__ out) {
    int g = blockIdx.x;
    int c = threadIdx.x;
    int a = 0, b = N_NODES;
    while (a < b) { int m = (a + b) >> 1; if (batch[m] < g) a = m + 1; else b = m; }
    int lo = a;
    b = N_NODES;
    while (a < b) { int m = (a + b) >> 1; if (batch[m] < g + 1) a = m + 1; else b = m; }
    int cnt = a - lo;
    out[g * 128 + c] = gsum[g * 128 + c] / fmaxf((float)cnt, 1.0f);
}

extern "C" void kernel_launch(void* const* d_in, const int* in_sizes, int n_in,
                              void* d_out, int out_size, void* d_ws, size_t ws_size,
                              hipStream_t stream) {
    const int*   z       = (const int*)  d_in[0];
    const float* pos     = (const float*)d_in[1];
    const int*   batch   = (const int*)  d_in[2];
    const int*   ei      = (const int*)  d_in[3];
    const float* emb     = (const float*)d_in[4];
    const float* mlp1_w  = (const float*)d_in[5];
    const float* mlp1_b  = (const float*)d_in[6];
    const float* mlp2_w  = (const float*)d_in[7];
    const float* mlp2_b  = (const float*)d_in[8];
    const float* cl1_w   = (const float*)d_in[9];
    const float* cl2_w   = (const float*)d_in[10];
    const float* cl2_b   = (const float*)d_in[11];
    const float* lin_w   = (const float*)d_in[12];
    const float* lin_b   = (const float*)d_in[13];
    const float* out1_w  = (const float*)d_in[14];
    const float* out1_b  = (const float*)d_in[15];
    const float* out2_w  = (const float*)d_in[16];
    const float* out2_b  = (const float*)d_in[17];

    float* ws     = (float*)d_ws;
    float* h      = ws;
    float* xhf    = h    + (size_t)N_NODES * HID;
    __half* xh    = (__half*)xhf;                   // N_NODES*HID halves (4 MB)
    float* agg    = xhf  + (size_t)N_NODES * HID;
    int2*  meta   = (int2*)(agg + (size_t)N_NODES * HID);
    int*   cnt    = (int*)(meta + N_EDGES);
    int*   rowptr = cnt + N_NODES;
    int*   wo     = rowptr + N_NODES + 1;
    float* gsum   = (float*)(wo + N_NODES);            // 64*128
    __half* ftab  = (__half*)(gsum + N_GRAPHS * 128);  // NL*TROWS*FILT halves

    hipMemsetAsync(cnt, 0, N_NODES * sizeof(int), stream);
    hipMemsetAsync(gsum, 0, N_GRAPHS * 128 * sizeof(float), stream);
    k_embed<<<N_NODES * HID / 256, 256, 0, stream>>>(z, emb, h);
    k_hist<<<N_EDGES / 256, 256, 0, stream>>>(ei, cnt);
    k_scan<<<1, 1024, 0, stream>>>(cnt, rowptr, wo);
    k_scatter<<<N_EDGES / 256, 256, 0, stream>>>(ei, pos, wo, meta);
    k_tab2<<<NL * TROWS / 16, 256, 0, stream>>>(mlp1_w, mlp1_b, mlp2_w, mlp2_b, ftab);

    k_gemm0<<<N_NODES / 16, 256, 0, stream>>>(h, cl1_w, xh);
    for (int i = 0; i < NL; ++i) {
        k_edge9<<<N_NODES / 4, 256, 0, stream>>>(
            meta, rowptr, xh, ftab + (size_t)i * TROWS * FILT, agg);
        if (i < NL - 1) {
            k_node5<true, true><<<N_NODES / 16, 256, 0, stream>>>(
                agg, cl2_w + (size_t)i * FILT * HID, cl2_b + (size_t)i * HID,
                lin_w + (size_t)i * HID * HID, lin_b + (size_t)i * HID,
                h, h, cl1_w + (size_t)(i + 1) * HID * FILT, xh);
        } else {
            k_node5<true, false><<<N_NODES / 16, 256, 0, stream>>>(
                agg, cl2_w + (size_t)i * FILT * HID, cl2_b + (size_t)i * HID,
                lin_w + (size_t)i * HID * HID, lin_b + (size_t)i * HID,
                h, h, nullptr, nullptr);
        }
    }
    // final MLP (fp32 out into agg), then pool
    k_node5<false, false><<<N_NODES / 16, 256, 0, stream>>>(
        h, out1_w, out1_b, out2_w, out2_b, nullptr, agg, nullptr, nullptr);
    k_pool2<<<N_NODES / 64, 128, 0, stream>>>(agg, batch, gsum);
    k_div<<<N_GRAPHS, 128, 0, stream>>>(gsum, batch, (float*)d_out);
}